// Round 10
// baseline (109.411 us; speedup 1.0000x reference)
//
#include <hip/hip_runtime.h>
#include <hip/hip_bf16.h>

#define NROW 8192
#define DDIM 512
#define MARGIN 0.2f

typedef __bf16 bf16x8 __attribute__((ext_vector_type(8)));
typedef float f32x4 __attribute__((ext_vector_type(4)));

__device__ __forceinline__ void gload16(const void* g, void* l) {
    __builtin_amdgcn_global_load_lds(
        (const __attribute__((address_space(1))) void*)g,
        (__attribute__((address_space(3))) void*)l, 16, 0, 0);
}

#define BAR() __builtin_amdgcn_s_barrier()

// ---------------------------------------------------------------------------
// prep: blocks 0..N-1 handle im (convert + idat={||im||^2, MARGIN+||im-s||}),
//       N..2N-1 handle ex (convert + ||ex||^2)
// ---------------------------------------------------------------------------
__global__ __launch_bounds__(256) void prep_kernel(
    const float* __restrict__ im, const float* __restrict__ s,
    const float* __restrict__ ex,
    ushort* __restrict__ Abf, ushort* __restrict__ Bbf,
    float2* __restrict__ idat, float* __restrict__ exsq) {
    int b = blockIdx.x;
    bool isim = b < NROW;
    int row = isim ? b : b - NROW;
    const float* src = isim ? im : ex;
    ushort* dst = isim ? Abf : Bbf;
    int tid = threadIdx.x;

    float2 v = ((const float2*)(src + (size_t)row * DDIM))[tid];
    __hip_bfloat16 hx = __float2bfloat16(v.x);
    __hip_bfloat16 hy = __float2bfloat16(v.y);
    unsigned packed = (unsigned)*(const ushort*)&hx | ((unsigned)*(const ushort*)&hy << 16);
    ((unsigned*)(dst + (size_t)row * DDIM))[tid] = packed;

    float ssq = v.x * v.x + v.y * v.y;
    float dsq = 0.f;
    if (isim) {
        float2 sv = ((const float2*)(s + (size_t)row * DDIM))[tid];
        float dx = v.x - sv.x, dy = v.y - sv.y;
        dsq = dx * dx + dy * dy;
    }
    #pragma unroll
    for (int off = 32; off > 0; off >>= 1) {
        ssq += __shfl_down(ssq, off);
        dsq += __shfl_down(dsq, off);
    }
    __shared__ float sred[8];
    int lane = tid & 63, w = tid >> 6;
    if (lane == 0) { sred[w] = ssq; sred[4 + w] = dsq; }
    __syncthreads();
    if (tid == 0) {
        float S = sred[0] + sred[1] + sred[2] + sred[3];
        float Dd = sred[4] + sred[5] + sred[6] + sred[7];
        if (isim) idat[row] = make_float2(S, MARGIN + sqrtf(Dd));
        else      exsq[row] = S;
    }
}

// ---------------------------------------------------------------------------
// 256x256 GEMM + fused epilogue. 8 waves (2Mx4N), BK=64, dbuf LDS.
// ONE phase per K-tile (round-9 showed the 4-phase BAR+lgkm(0) structure
// serializes the LDS-read pipe (~2300cyc/Ktile) with the MFMA pipe
// (~2490cyc/Ktile) -> 20% MfmaUtil). Now: issue all frag ds_reads, run all
// 64 MFMAs with compiler fine-grained lgkm waits (reads overlap MFMA),
// then BAR (reads all consumed -> safe overwrite), STAGE t+2, counted
// vmcnt(8) (seal t+1), BAR (block-wide seal: vmcnt is per-wave).
// LDS rows 128B with chunk16 swizzle: phys = logical ^ (row&7) (both sides).
// Half-tiles (16KB): id h = 4*ktile + q, q: 0=A-lo 1=A-hi 2=B-lo 3=B-hi.
// Block map: XCD c = bid0&7 owns bi in [4c,4c+4); 4x8 windows keep the ~32
// co-resident blocks/XCD at 1MB A + 2MB B < 4MB L2 (fixed 136->37MB fetch).
// ---------------------------------------------------------------------------
__global__ __launch_bounds__(512) void gemm_cost_kernel(
    const ushort* __restrict__ Abf, const ushort* __restrict__ Bbf,
    const float2* __restrict__ idat, const float* __restrict__ exsq,
    float* __restrict__ partials) {
    __shared__ __align__(16) ushort sA[2][16384];  // 64 KB
    __shared__ __align__(16) ushort sB[2][16384];  // 64 KB
    __shared__ float redbuf[8];

    // XCD-aware square-window mapping (bijective over 32x32 tiles)
    int bid0 = blockIdx.x;
    int c = bid0 & 7;            // assumed XCD id
    int sq = bid0 >> 3;          // 0..127 sequence within XCD
    int bi = c * 4 + (sq & 3);
    int bj = (sq >> 5) * 8 + ((sq >> 2) & 7);
    int bid = bi * 32 + bj;      // for partials indexing (bijective)
    int ibase = bi * 256, jbase = bj * 256;
    int tid = threadIdx.x, lane = tid & 63, w = tid >> 6;
    int wr = w >> 2, wc = w & 3;

    // staging per-thread constants
    int r = tid >> 3;            // 0..63 (second load: r+64)
    int pc = tid & 7;            // physical 16B chunk in row
    int lc = pc ^ (r & 7);       // logical chunk (source pre-swizzle)
    const ushort* aG = Abf + (size_t)(ibase + r) * DDIM + lc * 8;
    const ushort* bG = Bbf + (size_t)(jbase + r) * DDIM + lc * 8;
    ushort* aL = &sA[0][0] + r * 64 + pc * 8;
    ushort* bL = &sB[0][0] + r * 64 + pc * 8;

    auto STAGE = [&](int h) {
        if (h >= 32) return;
        int kt = h >> 2, q = h & 3;
        if (q < 2) {
            const ushort* g = aG + q * (128 * DDIM) + kt * 64;
            ushort* l = aL + (kt & 1) * 16384 + q * 8192;
            gload16(g, l);
            gload16(g + 64 * DDIM, l + 4096);
        } else {
            int qq = q - 2;
            const ushort* g = bG + qq * (128 * DDIM) + kt * 64;
            ushort* l = bL + (kt & 1) * 16384 + qq * 8192;
            gload16(g, l);
            gload16(g + 64 * DDIM, l + 4096);
        }
    };

    // ds_read per-thread constants (read-side swizzle: chunk ^= row&7 = lane&7)
    int l15 = lane & 15;
    int pc0 = (((lane >> 4) ^ (lane & 7)) * 8);  // ushort offset, ks=0
    int pc1 = pc0 ^ 32;                          // ks=1 (^4 chunks)
    int aoff = (wr * 128 + l15) * 64;
    int boff = (wc * 64 + l15) * 64;

    f32x4 acc[8][4] = {};

    // prologue: tiles 0 and 1 fully staged (16 loads); vmcnt(8) seals tile 0
    STAGE(0); STAGE(1); STAGE(2); STAGE(3);
    STAGE(4); STAGE(5); STAGE(6); STAGE(7);
    asm volatile("s_waitcnt vmcnt(8)" ::: "memory");
    BAR();

    #pragma unroll
    for (int t = 0; t < 8; ++t) {
        const ushort* pA = &sA[t & 1][0];
        const ushort* pB = &sB[t & 1][0];
        bf16x8 a[8][2], b0[2][2], b1[2][2];

        // all A fragments + first B pair (20 frags = 80 VGPR live)
        #pragma unroll
        for (int m = 0; m < 8; ++m) {
            a[m][0] = *(const bf16x8*)(pA + aoff + m * 1024 + pc0);
            a[m][1] = *(const bf16x8*)(pA + aoff + m * 1024 + pc1);
        }
        #pragma unroll
        for (int n = 0; n < 2; ++n) {
            b0[n][0] = *(const bf16x8*)(pB + boff + n * 1024 + pc0);
            b0[n][1] = *(const bf16x8*)(pB + boff + n * 1024 + pc1);
        }
        // Q(0,0)+Q(1,0): compiler inserts fine-grained lgkm waits; LDS reads
        // of later fragments continue landing during these MFMAs.
        __builtin_amdgcn_s_setprio(1);
        #pragma unroll
        for (int m = 0; m < 8; ++m)
            #pragma unroll
            for (int n = 0; n < 2; ++n) {
                acc[m][n] = __builtin_amdgcn_mfma_f32_16x16x32_bf16(a[m][0], b0[n][0], acc[m][n], 0, 0, 0);
                acc[m][n] = __builtin_amdgcn_mfma_f32_16x16x32_bf16(a[m][1], b0[n][1], acc[m][n], 0, 0, 0);
            }
        __builtin_amdgcn_s_setprio(0);
        // second B pair (b0 dead -> live count stays ~80)
        #pragma unroll
        for (int n = 0; n < 2; ++n) {
            b1[n][0] = *(const bf16x8*)(pB + boff + (n + 2) * 1024 + pc0);
            b1[n][1] = *(const bf16x8*)(pB + boff + (n + 2) * 1024 + pc1);
        }
        __builtin_amdgcn_s_setprio(1);
        #pragma unroll
        for (int m = 0; m < 8; ++m)
            #pragma unroll
            for (int n = 0; n < 2; ++n) {
                acc[m][n + 2] = __builtin_amdgcn_mfma_f32_16x16x32_bf16(a[m][0], b1[n][0], acc[m][n + 2], 0, 0, 0);
                acc[m][n + 2] = __builtin_amdgcn_mfma_f32_16x16x32_bf16(a[m][1], b1[n][1], acc[m][n + 2], 0, 0, 0);
            }
        __builtin_amdgcn_s_setprio(0);

        // all this wave's reads were consumed by issued MFMAs; barrier makes
        // that block-wide -> safe to overwrite buf[t&1] with tile t+2.
        BAR();
        STAGE(4 * (t + 2) + 0); STAGE(4 * (t + 2) + 1);
        STAGE(4 * (t + 2) + 2); STAGE(4 * (t + 2) + 3);
        if (t < 6)       asm volatile("s_waitcnt vmcnt(8)" ::: "memory");
        else if (t == 6) asm volatile("s_waitcnt vmcnt(0)" ::: "memory");
        BAR();   // block-wide seal of tile t+1 (vmcnt is per-wave)
    }

    // epilogue: cost = max(idat.y - sqrt(max(idat.x + exsq[j] - 2*dot, 0)), 0)
    // C/D layout: col = lane&15, row = (lane>>4)*4 + reg
    float jt[4];
    #pragma unroll
    for (int n = 0; n < 4; ++n) jt[n] = exsq[jbase + wc * 64 + n * 16 + l15];
    int r0 = (lane >> 4) * 4;
    float lsum = 0.f;
    #pragma unroll
    for (int m = 0; m < 8; ++m) {
        #pragma unroll
        for (int rg = 0; rg < 4; ++rg) {
            int i = ibase + wr * 128 + m * 16 + r0 + rg;
            float2 id = idat[i];
            #pragma unroll
            for (int n = 0; n < 4; ++n) {
                float d2 = fmaxf(id.x + jt[n] - 2.0f * acc[m][n][rg], 0.0f);
                lsum += fmaxf(id.y - sqrtf(d2), 0.0f);
            }
        }
    }
    #pragma unroll
    for (int off = 32; off > 0; off >>= 1) lsum += __shfl_down(lsum, off);
    if (lane == 0) redbuf[w] = lsum;
    __syncthreads();
    if (tid == 0) {
        float tot = 0.f;
        #pragma unroll
        for (int q = 0; q < 8; ++q) tot += redbuf[q];
        partials[bid] = tot;
    }
}

// ---------------------------------------------------------------------------
// deterministic final reduce: 1024 partials -> mean
// ---------------------------------------------------------------------------
__global__ __launch_bounds__(256) void finalize_kernel(
    const float* __restrict__ partials, float* __restrict__ out) {
    float acc = 0.f;
    for (int t = threadIdx.x; t < 1024; t += 256) acc += partials[t];
    #pragma unroll
    for (int off = 32; off > 0; off >>= 1) acc += __shfl_down(acc, off);
    __shared__ float sred[4];
    int lane = threadIdx.x & 63, w = threadIdx.x >> 6;
    if (lane == 0) sred[w] = acc;
    __syncthreads();
    if (threadIdx.x == 0) {
        float total = sred[0] + sred[1] + sred[2] + sred[3];
        out[0] = total * (1.0f / (8192.0f * 8192.0f));  // exact pow2 scale
    }
}

extern "C" void kernel_launch(void* const* d_in, const int* in_sizes, int n_in,
                              void* d_out, int out_size, void* d_ws, size_t ws_size,
                              hipStream_t stream) {
    const float* im = (const float*)d_in[0];
    const float* s  = (const float*)d_in[1];
    const float* ex = (const float*)d_in[2];

    // workspace layout (~16.2 MB)
    char* ws = (char*)d_ws;
    ushort* Abf   = (ushort*)(ws);                       // 8 MB
    ushort* Bbf   = (ushort*)(ws + 8388608);             // 8 MB
    float2* idat  = (float2*)(ws + 16777216);            // 64 KB
    float*  exsq  = (float*)(ws + 16842752);             // 32 KB
    float*  parts = (float*)(ws + 16875520);             // 4 KB

    prep_kernel<<<2 * NROW, 256, 0, stream>>>(im, s, ex, Abf, Bbf, idat, exsq);
    gemm_cost_kernel<<<(NROW / 256) * (NROW / 256), 512, 0, stream>>>(Abf, Bbf, idat, exsq, parts);
    finalize_kernel<<<1, 256, 0, stream>>>(parts, (float*)d_out);
}